// Round 2
// baseline (3035.631 us; speedup 1.0000x reference)
//
#include <hip/hip_runtime.h>

typedef _Float16 half8 __attribute__((ext_vector_type(8)));
typedef float f32x4 __attribute__((ext_vector_type(4)));

#define NT 512   // timesteps
#define NB 128   // batch
#define NI 256   // input dim
#define NH 512   // hidden dim
#define NG 8     // batch groups (16 rows each)
#define NS 8     // column slices (64 cols each)
#define FLAG_STRIDE 16  // ints -> 64B per flag, avoid line sharing

// ---------------------------------------------------------------------------
// W (fp32 [N][K]) -> fragment-linear f16 for MFMA B-operand.
// Block b = t_n*KT + t_k; lane l holds 8 elems: n = t_n*16 + (l&15),
// k = t_k*32 + (l>>4)*8 + j. Also zeroes the barrier flags (ws is 0xAA-poisoned).
// ---------------------------------------------------------------------------
__global__ void w_transform(const float* __restrict__ Whh,
                            const float* __restrict__ Win,
                            _Float16* __restrict__ Wf_hh,
                            _Float16* __restrict__ Wf_in,
                            int* __restrict__ flags) {
  int tid = blockIdx.x * blockDim.x + threadIdx.x;
  if (tid < 32768) {                    // W_hh: 32 n-tiles * 16 k-tiles
    int l = tid & 63, b = tid >> 6;
    int tk = b & 15, tn = b >> 4;
    int n = tn * 16 + (l & 15);
    int k = tk * 32 + (l >> 4) * 8;
    const float* src = Whh + (size_t)n * NH + k;
    _Float16* dst = Wf_hh + (size_t)tid * 8;
#pragma unroll
    for (int j = 0; j < 8; ++j) dst[j] = (_Float16)src[j];
  } else if (tid < 32768 + 16384) {     // W_in: 32 n-tiles * 8 k-tiles
    int t2 = tid - 32768;
    int l = t2 & 63, b = t2 >> 6;
    int tk = b & 7, tn = b >> 3;
    int n = tn * 16 + (l & 15);
    int k = tk * 32 + (l >> 4) * 8;
    const float* src = Win + (size_t)n * NI + k;
    _Float16* dst = Wf_in + (size_t)t2 * 8;
#pragma unroll
    for (int j = 0; j < 8; ++j) dst[j] = (_Float16)src[j];
  } else if (tid < 32768 + 16384 + NG * NS * FLAG_STRIDE) {
    flags[tid - 32768 - 16384] = 0;
  }
}

// ---------------------------------------------------------------------------
// Phase 1: xin = x @ W_in^T  (M=65536, K=256, N=512), fp32 out into d_out.
// ---------------------------------------------------------------------------
__global__ __launch_bounds__(256)
void input_proj(const float* __restrict__ x,
                const _Float16* __restrict__ Wf_in,
                float* __restrict__ xin) {
  int lane = threadIdx.x & 63;
  int wv = threadIdx.x >> 6;
  int m0 = blockIdx.x * 16;
  int c = lane & 15, q = lane >> 4;
  int row = m0 + c;

  f32x4 acc[8];
#pragma unroll
  for (int i = 0; i < 8; ++i) acc[i] = (f32x4){0.f, 0.f, 0.f, 0.f};

#pragma unroll
  for (int kc = 0; kc < 8; ++kc) {
    const float4* ap = (const float4*)(x + (size_t)row * NI + kc * 32 + q * 8);
    float4 a0 = ap[0], a1 = ap[1];
    half8 a;
    a[0] = (_Float16)a0.x; a[1] = (_Float16)a0.y;
    a[2] = (_Float16)a0.z; a[3] = (_Float16)a0.w;
    a[4] = (_Float16)a1.x; a[5] = (_Float16)a1.y;
    a[6] = (_Float16)a1.z; a[7] = (_Float16)a1.w;
#pragma unroll
    for (int nt = 0; nt < 8; ++nt) {
      int tn = wv * 8 + nt;
      const half8* bp =
          (const half8*)(Wf_in + (((size_t)(tn * 8 + kc)) * 64 + lane) * 8);
      acc[nt] = __builtin_amdgcn_mfma_f32_16x16x32_f16(a, *bp, acc[nt], 0, 0, 0);
    }
  }
#pragma unroll
  for (int nt = 0; nt < 8; ++nt) {
    int n = wv * 128 + nt * 16 + c;
#pragma unroll
    for (int r = 0; r < 4; ++r) {
      int m = q * 4 + r;
      xin[(size_t)(m0 + m) * NH + n] = acc[nt][r];
    }
  }
}

// ---------------------------------------------------------------------------
// Phase 2: recurrence on 64 wgs = 8 batch-groups x 8 col-slices.
// Each wave holds its 16-col weight slice in 64 VGPRs for all 512 steps
// (zero per-step weight traffic). Per step: 16 LDS A-reads + 16 MFMAs,
// fused relu/leak epilogue, f16 h-slice exchange through LLC (double-buffered,
// one flag barrier per step among the 8 slices of a group).
// ---------------------------------------------------------------------------
__global__ __launch_bounds__(256, 1)
void recurrence(float* __restrict__ dout,          // xin in-place -> h, + final
                const float* __restrict__ h0,
                const _Float16* __restrict__ Wf,   // fragment-linear W_hh
                _Float16* __restrict__ hbuf,       // [2][NB][NH] f16 exchange
                int* __restrict__ flags) {
  __shared__ _Float16 h_sh[16][520];   // full h rows for this group (A source)
  __shared__ float    h32[16][65];     // fp32 master, own 64-col slice

  int g = blockIdx.x >> 3, s = blockIdx.x & 7;
  int tid = threadIdx.x, lane = tid & 63, wv = tid >> 6;  // 4 waves
  int c = lane & 15, q = lane >> 4;
  int m0 = g * 16;                      // batch row base
  int n0 = s * 64;                      // hidden col base
  int ncol = wv * 16 + c;               // local col this thread epilogues

  // resident B-fragments: this wave's 16-col n-tile, all K (64 VGPRs/lane)
  int nt_global = s * 4 + wv;
  half8 bfrag[16];
#pragma unroll
  for (int kc = 0; kc < 16; ++kc)
    bfrag[kc] =
        *(const half8*)(Wf + (((size_t)(nt_global * 16 + kc)) * 64 + lane) * 8);

  // init h from h0
  for (int i = tid; i < 16 * 512; i += 256) {
    int m = i >> 9, n = i & 511;
    h_sh[m][n] = (_Float16)h0[(size_t)(m0 + m) * NH + n];
  }
  for (int i = tid; i < 16 * 64; i += 256) {
    int m = i >> 6, n = i & 63;
    h32[m][n] = h0[(size_t)(m0 + m) * NH + n0 + n];
  }
  __syncthreads();

  int* fbase = flags + g * NS * FLAG_STRIDE;
  unsigned short* hb16 = (unsigned short*)hbuf;

#pragma unroll 1
  for (int t = 0; t < NT; ++t) {
    // xin: 4 scattered dwords, same thread overwrites them in the epilogue
    const float* xp = dout + ((size_t)t * NB + m0) * NH + n0;
    float xv[4];
#pragma unroll
    for (int r = 0; r < 4; ++r) xv[r] = xp[(size_t)(q * 4 + r) * NH + ncol];

    // P = h @ Wslice^T, K=512; two acc chains to break MFMA dependency
    f32x4 acc0 = (f32x4){0.f, 0.f, 0.f, 0.f};
    f32x4 acc1 = (f32x4){0.f, 0.f, 0.f, 0.f};
#pragma unroll
    for (int kc = 0; kc < 16; kc += 2) {
      half8 a0 = *(const half8*)&h_sh[c][kc * 32 + q * 8];
      half8 a1 = *(const half8*)&h_sh[c][(kc + 1) * 32 + q * 8];
      acc0 = __builtin_amdgcn_mfma_f32_16x16x32_f16(a0, bfrag[kc], acc0, 0, 0, 0);
      acc1 = __builtin_amdgcn_mfma_f32_16x16x32_f16(a1, bfrag[kc + 1], acc1, 0, 0, 0);
    }
    __syncthreads();   // all h_sh reads done before refill overwrites

    // epilogue: h_new = relu(0.8 h + 0.2 (xin + P))
#pragma unroll
    for (int r = 0; r < 4; ++r) {
      int m = q * 4 + r;
      float hn = 0.8f * h32[m][ncol] + 0.2f * (xv[r] + acc0[r] + acc1[r]);
      hn = fmaxf(hn, 0.f);
      h32[m][ncol] = hn;
      dout[((size_t)t * NB + m0 + m) * NH + n0 + ncol] = hn;
      if (t == NT - 1) {
        dout[(size_t)NT * NB * NH + (size_t)(m0 + m) * NH + n0 + ncol] = hn;
      } else {
        unsigned short hbits = __builtin_bit_cast(unsigned short, (_Float16)hn);
        __hip_atomic_store(
            hb16 + ((size_t)(t & 1) * NB + m0 + m) * NH + n0 + ncol, hbits,
            __ATOMIC_RELAXED, __HIP_MEMORY_SCOPE_AGENT);
      }
    }
    if (t == NT - 1) break;

    __syncthreads();   // per-wave vmcnt drained at barrier: hbuf stores issued
    if (tid == 0)
      __hip_atomic_store(&fbase[s * FLAG_STRIDE], t + 1, __ATOMIC_RELEASE,
                         __HIP_MEMORY_SCOPE_AGENT);
    if (wv == 0 && lane < NS) {
      while (__hip_atomic_load(&fbase[lane * FLAG_STRIDE], __ATOMIC_ACQUIRE,
                               __HIP_MEMORY_SCOPE_AGENT) < t + 1) {
      }
    }
    __syncthreads();   // whole wg waits on wave0's poll

    // refill h_sh (16x512 f16 = 2048 8B words) from hbuf[t&1]
    {
      const unsigned long long* hb =
          (const unsigned long long*)hbuf +
          ((((size_t)(t & 1) * NB + m0) * NH) >> 2);
      for (int i = tid; i < 2048; i += 256) {
        int m = i >> 7, o = i & 127;
        unsigned long long v = __hip_atomic_load(
            hb + (size_t)m * 128 + o, __ATOMIC_RELAXED, __HIP_MEMORY_SCOPE_AGENT);
        *(unsigned long long*)&h_sh[m][o * 4] = v;
      }
    }
    __syncthreads();   // h_sh ready for next step's MFMA
  }
}

// ---------------------------------------------------------------------------
extern "C" void kernel_launch(void* const* d_in, const int* in_sizes, int n_in,
                              void* d_out, int out_size, void* d_ws,
                              size_t ws_size, hipStream_t stream) {
  const float* x      = (const float*)d_in[0];   // [512][128][256]
  const float* hidden = (const float*)d_in[1];   // [128][512]
  const float* W_in   = (const float*)d_in[2];   // [512][256]
  const float* W_hh   = (const float*)d_in[3];   // [512][512]
  float* out = (float*)d_out;

  // ws layout: Wf_hh 512KB | Wf_in 256KB (aliased by hbuf after input_proj) |
  //            flags 4KB
  _Float16* Wf_hh = (_Float16*)d_ws;
  _Float16* Wf_in = Wf_hh + (size_t)NH * NH;
  _Float16* hbuf  = Wf_in;                        // alias: safe, stream-ordered
  int* flags = (int*)((char*)d_ws + (size_t)NH * NH * 2 + (size_t)NH * NI * 2);

  w_transform<<<196, 256, 0, stream>>>(W_hh, W_in, Wf_hh, Wf_in, flags);
  input_proj<<<(NT * NB) / 16, 256, 0, stream>>>(x, Wf_in, out);

  void* args[] = {(void*)&out, (void*)&hidden, (void*)&Wf_hh, (void*)&hbuf,
                  (void*)&flags};
  hipLaunchCooperativeKernel((void*)recurrence, dim3(NG * NS), dim3(256), args,
                             0, stream);
}

// Round 3
// 1322.286 us; speedup vs baseline: 2.2957x; 2.2957x over previous
//
#include <hip/hip_runtime.h>

typedef _Float16 half8 __attribute__((ext_vector_type(8)));
typedef float f32x4 __attribute__((ext_vector_type(4)));

#define NT 512   // timesteps
#define NB 128   // batch
#define NI 256   // input dim
#define NH 512   // hidden dim
#define NG 8     // batch groups (16 rows each)
#define NS 8     // column slices (64 cols each)
#define FLAG_STRIDE 16  // ints -> 64B per flag, avoid line sharing

// ---------------------------------------------------------------------------
// W (fp32 [N][K]) -> fragment-linear f16 for MFMA B-operand.
// Block b = t_n*KT + t_k; lane l holds 8 elems: n = t_n*16 + (l&15),
// k = t_k*32 + (l>>4)*8 + j. Also zeroes the barrier flags (ws is 0xAA-poisoned).
// ---------------------------------------------------------------------------
__global__ void w_transform(const float* __restrict__ Whh,
                            const float* __restrict__ Win,
                            _Float16* __restrict__ Wf_hh,
                            _Float16* __restrict__ Wf_in,
                            int* __restrict__ flags) {
  int tid = blockIdx.x * blockDim.x + threadIdx.x;
  if (tid < 32768) {                    // W_hh: 32 n-tiles * 16 k-tiles
    int l = tid & 63, b = tid >> 6;
    int tk = b & 15, tn = b >> 4;
    int n = tn * 16 + (l & 15);
    int k = tk * 32 + (l >> 4) * 8;
    const float* src = Whh + (size_t)n * NH + k;
    _Float16* dst = Wf_hh + (size_t)tid * 8;
#pragma unroll
    for (int j = 0; j < 8; ++j) dst[j] = (_Float16)src[j];
  } else if (tid < 32768 + 16384) {     // W_in: 32 n-tiles * 8 k-tiles
    int t2 = tid - 32768;
    int l = t2 & 63, b = t2 >> 6;
    int tk = b & 7, tn = b >> 3;
    int n = tn * 16 + (l & 15);
    int k = tk * 32 + (l >> 4) * 8;
    const float* src = Win + (size_t)n * NI + k;
    _Float16* dst = Wf_in + (size_t)t2 * 8;
#pragma unroll
    for (int j = 0; j < 8; ++j) dst[j] = (_Float16)src[j];
  } else if (tid < 32768 + 16384 + NG * NS * FLAG_STRIDE) {
    flags[tid - 32768 - 16384] = 0;
  }
}

// ---------------------------------------------------------------------------
// Phase 1: xin = x @ W_in^T  (M=65536, K=256, N=512), fp32 out into d_out.
// ---------------------------------------------------------------------------
__global__ __launch_bounds__(256)
void input_proj(const float* __restrict__ x,
                const _Float16* __restrict__ Wf_in,
                float* __restrict__ xin) {
  int lane = threadIdx.x & 63;
  int wv = threadIdx.x >> 6;
  int m0 = blockIdx.x * 16;
  int c = lane & 15, q = lane >> 4;
  int row = m0 + c;

  f32x4 acc[8];
#pragma unroll
  for (int i = 0; i < 8; ++i) acc[i] = (f32x4){0.f, 0.f, 0.f, 0.f};

#pragma unroll
  for (int kc = 0; kc < 8; ++kc) {
    const float4* ap = (const float4*)(x + (size_t)row * NI + kc * 32 + q * 8);
    float4 a0 = ap[0], a1 = ap[1];
    half8 a;
    a[0] = (_Float16)a0.x; a[1] = (_Float16)a0.y;
    a[2] = (_Float16)a0.z; a[3] = (_Float16)a0.w;
    a[4] = (_Float16)a1.x; a[5] = (_Float16)a1.y;
    a[6] = (_Float16)a1.z; a[7] = (_Float16)a1.w;
#pragma unroll
    for (int nt = 0; nt < 8; ++nt) {
      int tn = wv * 8 + nt;
      const half8* bp =
          (const half8*)(Wf_in + (((size_t)(tn * 8 + kc)) * 64 + lane) * 8);
      acc[nt] = __builtin_amdgcn_mfma_f32_16x16x32_f16(a, *bp, acc[nt], 0, 0, 0);
    }
  }
#pragma unroll
  for (int nt = 0; nt < 8; ++nt) {
    int n = wv * 128 + nt * 16 + c;
#pragma unroll
    for (int r = 0; r < 4; ++r) {
      int m = q * 4 + r;
      xin[(size_t)(m0 + m) * NH + n] = acc[nt][r];
    }
  }
}

// ---------------------------------------------------------------------------
// Phase 2: recurrence, 64 wgs = 8 batch-groups x 8 col-slices. Weights stay
// in VGPRs all 512 steps. Cross-slice h exchange is RELAXED sc1 atomics only
// (no acquire/release -> no buffer_inv / buffer_wbl2 L2 nukes). Ordering:
// the compiler drains vmcnt(0) before s_barrier, so all hbuf stores are
// LLC-visible before tid0 publishes the flag.
// ---------------------------------------------------------------------------
__global__ __launch_bounds__(256, 1)
void recurrence(float* __restrict__ dout,          // xin in-place -> h, + final
                const float* __restrict__ h0,
                const _Float16* __restrict__ Wf,   // fragment-linear W_hh
                _Float16* __restrict__ hbuf,       // [2][NB][NH] f16 exchange
                int* __restrict__ flags) {
  __shared__ _Float16 h_sh[16][520];   // full h rows (A source), 16B-aligned rows
  __shared__ _Float16 h16s[16][72];    // epilogue->exchange bounce (2 KB)

  int g = blockIdx.x >> 3, s = blockIdx.x & 7;
  int tid = threadIdx.x, lane = tid & 63, wv = tid >> 6;  // 4 waves
  int c = lane & 15, q = lane >> 4;
  int m0 = g * 16;                      // batch row base
  int n0 = s * 64;                      // hidden col base
  int ncol = wv * 16 + c;               // local col this thread epilogues

  // resident B-fragments: this wave's 16-col n-tile, all K (64 VGPRs/lane)
  int nt_global = s * 4 + wv;
  half8 bfrag[16];
#pragma unroll
  for (int kc = 0; kc < 16; ++kc)
    bfrag[kc] =
        *(const half8*)(Wf + (((size_t)(nt_global * 16 + kc)) * 64 + lane) * 8);

  // fp32 master state: this thread's 4 rows x 1 col (matches C-fragment)
  float h32r[4];
#pragma unroll
  for (int r = 0; r < 4; ++r)
    h32r[r] = h0[(size_t)(m0 + q * 4 + r) * NH + n0 + ncol];

  // init h_sh from h0
  for (int i = tid; i < 16 * 512; i += 256) {
    int m = i >> 9, n = i & 511;
    h_sh[m][n] = (_Float16)h0[(size_t)(m0 + m) * NH + n];
  }
  __syncthreads();

  int* fbase = flags + g * NS * FLAG_STRIDE;
  unsigned long long* hb64 = (unsigned long long*)hbuf;

  // copy-out addressing (thread i handles row i>>4, 4-col chunk i&15)
  int cm = tid >> 4, cc = tid & 15;

#pragma unroll 1
  for (int t = 0; t < NT; ++t) {
    // xin: 4 scattered dwords, same thread overwrites them in the epilogue
    const float* xp = dout + ((size_t)t * NB + m0) * NH + n0;
    float xv[4];
#pragma unroll
    for (int r = 0; r < 4; ++r) xv[r] = xp[(size_t)(q * 4 + r) * NH + ncol];

    // P = h @ Wslice^T, K=512; two acc chains
    f32x4 acc0 = (f32x4){0.f, 0.f, 0.f, 0.f};
    f32x4 acc1 = (f32x4){0.f, 0.f, 0.f, 0.f};
#pragma unroll
    for (int kc = 0; kc < 16; kc += 2) {
      half8 a0 = *(const half8*)&h_sh[c][kc * 32 + q * 8];
      half8 a1 = *(const half8*)&h_sh[c][(kc + 1) * 32 + q * 8];
      acc0 = __builtin_amdgcn_mfma_f32_16x16x32_f16(a0, bfrag[kc], acc0, 0, 0, 0);
      acc1 = __builtin_amdgcn_mfma_f32_16x16x32_f16(a1, bfrag[kc + 1], acc1, 0, 0, 0);
    }

    // epilogue: h_new = relu(0.8 h + 0.2 (xin + P))
#pragma unroll
    for (int r = 0; r < 4; ++r) {
      int m = q * 4 + r;
      float hn = 0.8f * h32r[r] + 0.2f * (xv[r] + acc0[r] + acc1[r]);
      hn = fmaxf(hn, 0.f);
      h32r[r] = hn;
      dout[((size_t)t * NB + m0 + m) * NH + n0 + ncol] = hn;
      h16s[m][ncol] = (_Float16)hn;
      if (t == NT - 1)
        dout[(size_t)NT * NB * NH + (size_t)(m0 + m) * NH + n0 + ncol] = hn;
    }
    if (t == NT - 1) break;

    __syncthreads();  // (a) h16s complete; also all h_sh MFMA reads done

    // coalesced exchange store: 256 threads x 8B, 128B-contiguous per row
    {
      unsigned long long v = *(const unsigned long long*)&h16s[cm][cc * 4];
      __hip_atomic_store(
          hb64 + ((((size_t)(t & 1) * NB + m0 + cm) * NH + n0 + cc * 4) >> 2),
          v, __ATOMIC_RELAXED, __HIP_MEMORY_SCOPE_AGENT);
    }
    __syncthreads();  // (b) barrier drains vmcnt(0): stores are LLC-visible

    if (tid == 0)
      __hip_atomic_store(&fbase[s * FLAG_STRIDE], t + 1, __ATOMIC_RELAXED,
                         __HIP_MEMORY_SCOPE_AGENT);
    if (wv == 0 && lane < NS) {
      while (__hip_atomic_load(&fbase[lane * FLAG_STRIDE], __ATOMIC_RELAXED,
                               __HIP_MEMORY_SCOPE_AGENT) < t + 1) {
      }
    }
    __syncthreads();  // (c) all slices published step t+1

    // refill h_sh: 16 KB, 8 independent 8B sc1 loads/thread, then LDS stores
    {
      const unsigned long long* hb =
          hb64 + ((((size_t)(t & 1) * NB + m0) * NH) >> 2);
      unsigned long long v[8];
#pragma unroll
      for (int j = 0; j < 8; ++j) {
        int k = tid + j * 256;          // 0..2047 8B chunks
        v[j] = __hip_atomic_load(hb + k, __ATOMIC_RELAXED,
                                 __HIP_MEMORY_SCOPE_AGENT);
      }
#pragma unroll
      for (int j = 0; j < 8; ++j) {
        int k = tid + j * 256;
        int m = k >> 7, o = k & 127;    // 128 8B-chunks per 512-col row
        *(unsigned long long*)&h_sh[m][o * 4] = v[j];
      }
    }
    __syncthreads();  // (d) h_sh ready for next step
  }
}

// ---------------------------------------------------------------------------
extern "C" void kernel_launch(void* const* d_in, const int* in_sizes, int n_in,
                              void* d_out, int out_size, void* d_ws,
                              size_t ws_size, hipStream_t stream) {
  const float* x      = (const float*)d_in[0];   // [512][128][256]
  const float* hidden = (const float*)d_in[1];   // [128][512]
  const float* W_in   = (const float*)d_in[2];   // [512][256]
  const float* W_hh   = (const float*)d_in[3];   // [512][512]
  float* out = (float*)d_out;

  // ws layout: Wf_hh 512KB | Wf_in 256KB (aliased by hbuf after input_proj) |
  //            flags 4KB
  _Float16* Wf_hh = (_Float16*)d_ws;
  _Float16* Wf_in = Wf_hh + (size_t)NH * NH;
  _Float16* hbuf  = Wf_in;                        // alias: safe, stream-ordered
  int* flags = (int*)((char*)d_ws + (size_t)NH * NH * 2 + (size_t)NH * NI * 2);

  w_transform<<<196, 256, 0, stream>>>(W_hh, W_in, Wf_hh, Wf_in, flags);
  input_proj<<<(NT * NB) / 16, 256, 0, stream>>>(x, Wf_in, out);

  void* args[] = {(void*)&out, (void*)&hidden, (void*)&Wf_hh, (void*)&hbuf,
                  (void*)&flags};
  hipLaunchCooperativeKernel((void*)recurrence, dim3(NG * NS), dim3(256), args,
                             0, stream);
}